// Round 9
// baseline (202.844 us; speedup 1.0000x reference)
//
#include <hip/hip_runtime.h>

#define N_NODES 100000
#define F_IN 128
#define F_HID 32
#define BN 128                  // nodes per bucket (pow2)
#define NBUCK 782               // ceil(100000/128)
#define NBLK 128                // edge partition chunks (16 entries/bucket avg -> 64B runs)
#define G1_BLOCK 128
#define G1_NODES 64             // nodes per gemm1 block

// ---------------- phase A: bucket partition of edges (no global atomics) ----------------

__global__ __launch_bounds__(256) void part_count(const int* __restrict__ src,
                                                  const int* __restrict__ dst, int E,
                                                  unsigned* __restrict__ cntD,
                                                  unsigned* __restrict__ cntS) {
    __shared__ unsigned cd[NBUCK], cs[NBUCK];
    for (int i = threadIdx.x; i < NBUCK; i += 256) { cd[i] = 0; cs[i] = 0; }
    __syncthreads();
    int chunk = (E + NBLK - 1) / NBLK;
    int e0 = blockIdx.x * chunk, e1 = min(E, e0 + chunk);
    for (int e = e0 + threadIdx.x; e < e1; e += 256) {
        atomicAdd(&cd[((unsigned)dst[e]) >> 7], 1u);   // LDS atomic
        atomicAdd(&cs[((unsigned)src[e]) >> 7], 1u);
    }
    __syncthreads();
    unsigned* od = cntD + (size_t)blockIdx.x * NBUCK;
    unsigned* os = cntS + (size_t)blockIdx.x * NBUCK;
    for (int i = threadIdx.x; i < NBUCK; i += 256) { od[i] = cd[i]; os[i] = cs[i]; }
}

// per-bucket exclusive scan over blocks (in place); totals[k] = bucket size
__global__ __launch_bounds__(NBLK) void col_scan(unsigned* __restrict__ cnt,
                                                 unsigned* __restrict__ totals) {
    __shared__ unsigned buf[2][NBLK];
    int k = blockIdx.x, t = threadIdx.x;
    unsigned v = cnt[(size_t)t * NBUCK + k];
    buf[0][t] = v;
    __syncthreads();
    int cur = 0;
    for (int off = 1; off < NBLK; off <<= 1) {
        unsigned x = buf[cur][t];
        if (t >= off) x += buf[cur][t - off];
        buf[cur ^ 1][t] = x;
        cur ^= 1;
        __syncthreads();
    }
    cnt[(size_t)t * NBUCK + k] = buf[cur][t] - v;  // exclusive over blocks
    if (t == NBLK - 1) totals[k] = buf[cur][NBLK - 1];
}

// exclusive scan of bucket totals -> start[0..NBUCK] (start[NBUCK] = E)
__global__ __launch_bounds__(1024) void total_scan(const unsigned* __restrict__ totals,
                                                   unsigned* __restrict__ start) {
    __shared__ unsigned buf[2][1024];
    int t = threadIdx.x;
    buf[0][t] = (t < NBUCK) ? totals[t] : 0;
    __syncthreads();
    int cur = 0;
    for (int off = 1; off < 1024; off <<= 1) {
        unsigned x = buf[cur][t];
        if (t >= off) x += buf[cur][t - off];
        buf[cur ^ 1][t] = x;
        cur ^= 1;
        __syncthreads();
    }
    if (t < NBUCK) start[t + 1] = buf[cur][t];
    if (t == 0) start[0] = 0;
}

// scatter edges into bucket-partitioned layout; slots disjoint by construction
__global__ __launch_bounds__(256) void part_scatter(const int* __restrict__ src,
                                                    const int* __restrict__ dst, int E,
                                                    const unsigned* __restrict__ cntD,
                                                    const unsigned* __restrict__ cntS,
                                                    const unsigned* __restrict__ startD,
                                                    const unsigned* __restrict__ startS,
                                                    unsigned* __restrict__ pairD,
                                                    unsigned* __restrict__ valS) {
    __shared__ unsigned curD[NBUCK], curS[NBUCK];
    for (int i = threadIdx.x; i < NBUCK; i += 256) { curD[i] = 0; curS[i] = 0; }
    __syncthreads();
    int chunk = (E + NBLK - 1) / NBLK;
    int e0 = blockIdx.x * chunk, e1 = min(E, e0 + chunk);
    const unsigned* bd = cntD + (size_t)blockIdx.x * NBUCK;
    const unsigned* bs = cntS + (size_t)blockIdx.x * NBUCK;
    for (int e = e0 + threadIdx.x; e < e1; e += 256) {
        unsigned s = (unsigned)src[e], d = (unsigned)dst[e];
        unsigned kd = d >> 7, ks = s >> 7;
        unsigned rd = atomicAdd(&curD[kd], 1u);                 // LDS rank
        pairD[startD[kd] + bd[kd] + rd] = s | ((d & 127u) << 17);
        unsigned rs = atomicAdd(&curS[ks], 1u);
        valS[startS[ks] + bs[ks] + rs] = s & 127u;
    }
}

// ---------------- phase B: per-bucket counting sort -> full CSR (no global atomics) ----------

__global__ __launch_bounds__(256) void bucket_sort(const unsigned* __restrict__ pairD,
                                                   const unsigned* __restrict__ startD,
                                                   int* __restrict__ col, int* __restrict__ row_ptr,
                                                   int* __restrict__ deg_arr,
                                                   float* __restrict__ norm_in, int n) {
    __shared__ unsigned cnt[BN];
    __shared__ unsigned base[BN];
    __shared__ unsigned sbuf[2][BN];
    int t = threadIdx.x;
    if (t < BN) cnt[t] = 0;
    __syncthreads();
    int k = blockIdx.x;
    unsigned a0 = startD[k], a1 = startD[k + 1];
    for (unsigned i = a0 + t; i < a1; i += 256)
        atomicAdd(&cnt[(pairD[i] >> 17) & 127u], 1u);
    __syncthreads();
    unsigned v = (t < BN) ? cnt[t] : 0;
    if (t < BN) sbuf[0][t] = v;
    __syncthreads();
    int cur = 0;
    for (int off = 1; off < BN; off <<= 1) {
        if (t < BN) {
            unsigned x = sbuf[cur][t];
            if (t >= off) x += sbuf[cur][t - off];
            sbuf[cur ^ 1][t] = x;
        }
        cur ^= 1;
        __syncthreads();
    }
    if (t < BN) {
        base[t] = a0 + sbuf[cur][t] - v;  // exclusive within bucket
        int node = k * BN + t;
        if (node < n) {
            row_ptr[node] = (int)base[t];
            deg_arr[node] = (int)v;
            norm_in[node] = rsqrtf((float)(v > 1u ? v : 1u));
        }
        cnt[t] = 0;  // reuse as cursor
    }
    __syncthreads();
    for (unsigned i = a0 + t; i < a1; i += 256) {
        unsigned pv = pairD[i];
        unsigned l = (pv >> 17) & 127u;
        unsigned r = atomicAdd(&cnt[l], 1u);   // LDS rank
        col[base[l] + r] = (int)(pv & 0x1FFFFu);
    }
}

// src-side degree -> norm_out
__global__ __launch_bounds__(256) void bucket_norms_src(const unsigned* __restrict__ valS,
                                                        const unsigned* __restrict__ startS,
                                                        float* __restrict__ norm_out, int n) {
    __shared__ unsigned cnt[BN];
    if (threadIdx.x < BN) cnt[threadIdx.x] = 0;
    __syncthreads();
    int k = blockIdx.x;
    unsigned a0 = startS[k], a1 = startS[k + 1];
    for (unsigned i = a0 + threadIdx.x; i < a1; i += 256)
        atomicAdd(&cnt[valS[i]], 1u);
    __syncthreads();
    if (threadIdx.x < BN) {
        int node = k * BN + threadIdx.x;
        if (node < n) {
            unsigned c = cnt[threadIdx.x];
            norm_out[node] = rsqrtf((float)(c > 1u ? c : 1u));
        }
    }
}

// ---------------- layer-1 projection: 4-node register blocking, x+W in LDS ----------------

__device__ __forceinline__ void fma4(float4& a, float s, float4 w) {
    a.x += s * w.x; a.y += s * w.y; a.z += s * w.z; a.w += s * w.w;
}

// h[node] = (x[node] @ W1) * norm_out[node]; thread = 4 nodes x 4 outputs
__global__ __launch_bounds__(G1_BLOCK) void gemm1_kernel(const float* __restrict__ x,
                                                         const float* __restrict__ W,
                                                         const float* __restrict__ norm_out,
                                                         float* __restrict__ h, int n) {
    __shared__ float4 Xs[G1_NODES * 32];  // 32 KB: 64 rows of 128 floats
    __shared__ float4 Ws[F_IN * 8];       // 16 KB: W[k][j] as float4 along j
    const float4* W4 = reinterpret_cast<const float4*>(W);
    for (int i = threadIdx.x; i < F_IN * 8; i += G1_BLOCK) Ws[i] = W4[i];
    int nb = blockIdx.x * G1_NODES;
    int nrows = n - nb; if (nrows > G1_NODES) nrows = G1_NODES;
    const float4* x4 = reinterpret_cast<const float4*>(x + (size_t)nb * F_IN);
    for (int i = threadIdx.x; i < nrows * 32; i += G1_BLOCK) Xs[i] = x4[i];
    __syncthreads();
    int q = threadIdx.x & 7;      // output quad: j = 4q..4q+3
    int g = threadIdx.x >> 3;     // node group 0..15
    int l0 = g * 4;
    float4 acc0 = make_float4(0.f, 0.f, 0.f, 0.f);
    float4 acc1 = acc0, acc2 = acc0, acc3 = acc0;
#pragma unroll 4
    for (int k4 = 0; k4 < 32; ++k4) {
        float4 xv0 = Xs[(l0 + 0) * 32 + k4];
        float4 xv1 = Xs[(l0 + 1) * 32 + k4];
        float4 xv2 = Xs[(l0 + 2) * 32 + k4];
        float4 xv3 = Xs[(l0 + 3) * 32 + k4];
        float4 w0 = Ws[(k4 * 4 + 0) * 8 + q];
        float4 w1 = Ws[(k4 * 4 + 1) * 8 + q];
        float4 w2 = Ws[(k4 * 4 + 2) * 8 + q];
        float4 w3 = Ws[(k4 * 4 + 3) * 8 + q];
        fma4(acc0, xv0.x, w0); fma4(acc0, xv0.y, w1); fma4(acc0, xv0.z, w2); fma4(acc0, xv0.w, w3);
        fma4(acc1, xv1.x, w0); fma4(acc1, xv1.y, w1); fma4(acc1, xv1.z, w2); fma4(acc1, xv1.w, w3);
        fma4(acc2, xv2.x, w0); fma4(acc2, xv2.y, w1); fma4(acc2, xv2.z, w2); fma4(acc2, xv2.w, w3);
        fma4(acc3, xv3.x, w0); fma4(acc3, xv3.y, w1); fma4(acc3, xv3.z, w2); fma4(acc3, xv3.w, w3);
    }
    float4* h4 = reinterpret_cast<float4*>(h);
    float4 accs[4] = {acc0, acc1, acc2, acc3};
#pragma unroll
    for (int i = 0; i < 4; ++i) {
        int node = nb + l0 + i;
        if (node < n) {
            float no = norm_out[node];
            float4 o = accs[i];
            o.x *= no; o.y *= no; o.z *= no; o.w *= no;
            h4[(size_t)node * 8 + q] = o;
        }
    }
}

// ---------------- gather aggregation: 8 lanes/node, float4/lane, 8-edge unroll --------------

__device__ __forceinline__ float4 shfl4_8(float4 v, int sl) {
    float4 r;
    r.x = __shfl(v.x, sl, 8);
    r.y = __shfl(v.y, sl, 8);
    r.z = __shfl(v.z, sl, 8);
    r.w = __shfl(v.w, sl, 8);
    return r;
}

// layer 1: agg + norm_in + b1 + relu, GEMM2 (8-lane shfl), prescale norm_out -> h2s
__global__ __launch_bounds__(256) void agg1_kernel(const float* __restrict__ h1s,
                                                   const int* __restrict__ row_ptr,
                                                   const int* __restrict__ deg_arr,
                                                   const int* __restrict__ col,
                                                   const float* __restrict__ norm_in,
                                                   const float* __restrict__ norm_out,
                                                   const float* __restrict__ b1,
                                                   const float* __restrict__ W2,
                                                   float* __restrict__ h2s, int n) {
    __shared__ float W2l[F_HID * F_HID];  // row k holds W2[k][0..31]
    for (int i = threadIdx.x; i < F_HID * F_HID; i += 256) W2l[i] = W2[i];
    __syncthreads();
    const float4* h4 = reinterpret_cast<const float4*>(h1s);
    const float4* W24 = reinterpret_cast<const float4*>(W2l);
    int q = threadIdx.x & 7;                 // lane in 8-lane group
    int node = blockIdx.x * 32 + (threadIdx.x >> 3);
    if (node >= n) return;
    int start = row_ptr[node];
    int deg = deg_arr[node];
    float4 acc = make_float4(0.f, 0.f, 0.f, 0.f);
    int jj = 0;
    for (; jj + 8 <= deg; jj += 8) {
        int c = col[start + jj + q];         // 8 lanes: one coalesced 32B load
#pragma unroll
        for (int m = 0; m < 8; ++m) {
            int s = __shfl(c, m, 8);
            float4 v = h4[(size_t)s * 8 + q];
            acc.x += v.x; acc.y += v.y; acc.z += v.z; acc.w += v.w;
        }
    }
    int rem = deg - jj;
    if (rem > 0) {
        int c = col[start + jj + (q < rem ? q : 0)];
        for (int m = 0; m < rem; ++m) {
            int s = __shfl(c, m, 8);
            float4 v = h4[(size_t)s * 8 + q];
            acc.x += v.x; acc.y += v.y; acc.z += v.z; acc.w += v.w;
        }
    }
    float ni = norm_in[node];
    const float4 b14 = reinterpret_cast<const float4*>(b1)[q];
    float4 t;
    t.x = fmaxf(acc.x * ni + b14.x, 0.f);
    t.y = fmaxf(acc.y * ni + b14.y, 0.f);
    t.z = fmaxf(acc.z * ni + b14.z, 0.f);
    t.w = fmaxf(acc.w * ni + b14.w, 0.f);
    // GEMM2: o[f] = sum_k t[k] * W2[k][f]; t distributed 4-per-lane over 8 lanes
    float4 o = make_float4(0.f, 0.f, 0.f, 0.f);
#pragma unroll
    for (int sl = 0; sl < 8; ++sl) {
        float4 tt = shfl4_8(t, sl);
        int kb = sl * 4;
        float4 w0 = W24[(kb + 0) * 8 + q];
        float4 w1 = W24[(kb + 1) * 8 + q];
        float4 w2 = W24[(kb + 2) * 8 + q];
        float4 w3 = W24[(kb + 3) * 8 + q];
        o.x += tt.x * w0.x + tt.y * w1.x + tt.z * w2.x + tt.w * w3.x;
        o.y += tt.x * w0.y + tt.y * w1.y + tt.z * w2.y + tt.w * w3.y;
        o.z += tt.x * w0.z + tt.y * w1.z + tt.z * w2.z + tt.w * w3.z;
        o.w += tt.x * w0.w + tt.y * w1.w + tt.z * w2.w + tt.w * w3.w;
    }
    float no = norm_out[node];
    o.x *= no; o.y *= no; o.z *= no; o.w *= no;
    reinterpret_cast<float4*>(h2s)[(size_t)node * 8 + q] = o;
}

// layer 2: agg + norm_in + b2 -> out
__global__ __launch_bounds__(256) void agg2_kernel(const float* __restrict__ h2s,
                                                   const int* __restrict__ row_ptr,
                                                   const int* __restrict__ deg_arr,
                                                   const int* __restrict__ col,
                                                   const float* __restrict__ norm_in,
                                                   const float* __restrict__ b2,
                                                   float* __restrict__ out, int n) {
    const float4* h4 = reinterpret_cast<const float4*>(h2s);
    int q = threadIdx.x & 7;
    int node = blockIdx.x * 32 + (threadIdx.x >> 3);
    if (node >= n) return;
    int start = row_ptr[node];
    int deg = deg_arr[node];
    float4 acc = make_float4(0.f, 0.f, 0.f, 0.f);
    int jj = 0;
    for (; jj + 8 <= deg; jj += 8) {
        int c = col[start + jj + q];
#pragma unroll
        for (int m = 0; m < 8; ++m) {
            int s = __shfl(c, m, 8);
            float4 v = h4[(size_t)s * 8 + q];
            acc.x += v.x; acc.y += v.y; acc.z += v.z; acc.w += v.w;
        }
    }
    int rem = deg - jj;
    if (rem > 0) {
        int c = col[start + jj + (q < rem ? q : 0)];
        for (int m = 0; m < rem; ++m) {
            int s = __shfl(c, m, 8);
            float4 v = h4[(size_t)s * 8 + q];
            acc.x += v.x; acc.y += v.y; acc.z += v.z; acc.w += v.w;
        }
    }
    float ni = norm_in[node];
    const float4 b24 = reinterpret_cast<const float4*>(b2)[q];
    float4 o;
    o.x = acc.x * ni + b24.x;
    o.y = acc.y * ni + b24.y;
    o.z = acc.z * ni + b24.z;
    o.w = acc.w * ni + b24.w;
    reinterpret_cast<float4*>(out)[(size_t)node * 8 + q] = o;
}

// ---------------- launch ----------------

static inline size_t align256(size_t x) { return (x + 255) & ~(size_t)255; }

extern "C" void kernel_launch(void* const* d_in, const int* in_sizes, int n_in,
                              void* d_out, int out_size, void* d_ws, size_t ws_size,
                              hipStream_t stream) {
    const float* features = (const float*)d_in[0];
    const float* W1 = (const float*)d_in[1];
    const float* b1 = (const float*)d_in[2];
    const float* W2 = (const float*)d_in[3];
    const float* b2 = (const float*)d_in[4];
    const int* src = (const int*)d_in[5];
    const int* dst = (const int*)d_in[6];
    const int E = in_sizes[5];
    const int n = N_NODES;
    float* out = (float*)d_out;

    char* ws = (char*)d_ws;
    size_t off = 0;
    float* norm_out = (float*)(ws + off); off += align256((size_t)n * 4);
    float* norm_in = (float*)(ws + off);  off += align256((size_t)n * 4);
    int* row_ptr = (int*)(ws + off);      off += align256((size_t)n * 4);
    int* deg_arr = (int*)(ws + off);      off += align256((size_t)n * 4);
    unsigned* startD = (unsigned*)(ws + off); off += align256((NBUCK + 1) * 4);
    unsigned* startS = (unsigned*)(ws + off); off += align256((NBUCK + 1) * 4);
    unsigned* totD = (unsigned*)(ws + off);   off += align256(NBUCK * 4);
    unsigned* totS = (unsigned*)(ws + off);   off += align256(NBUCK * 4);
    int* col = (int*)(ws + off);              off += align256((size_t)E * 4);  // 6.4 MB

    // region X: pairD+valS (live: part_scatter -> bucket kernels) then h2s (live: agg1 -> agg2)
    size_t regX = off;
    unsigned* pairD = (unsigned*)(ws + regX);                        // 6.4 MB
    unsigned* valS = (unsigned*)(ws + regX + (size_t)E * 4);         // 6.4 MB
    float* h2s = (float*)(ws + regX);                                // 12.8 MB
    off += align256((size_t)2 * E * 4);
    // region Y: cntD+cntS (live: part_count -> part_scatter) then h1s (live: gemm1 -> agg1)
    size_t regY = off;
    unsigned* cntD = (unsigned*)(ws + regY);                         // 0.4 MB
    unsigned* cntS = (unsigned*)(ws + regY + (size_t)NBLK * NBUCK * 4);
    float* h1s = (float*)(ws + regY);                                // 12.8 MB

    // phase A: partition edges by dst-bucket (pairs) and src-bucket (locals)
    part_count<<<NBLK, 256, 0, stream>>>(src, dst, E, cntD, cntS);
    col_scan<<<NBUCK, NBLK, 0, stream>>>(cntD, totD);
    col_scan<<<NBUCK, NBLK, 0, stream>>>(cntS, totS);
    total_scan<<<1, 1024, 0, stream>>>(totD, startD);
    total_scan<<<1, 1024, 0, stream>>>(totS, startS);
    part_scatter<<<NBLK, 256, 0, stream>>>(src, dst, E, cntD, cntS, startD, startS, pairD, valS);

    // phase B: per-bucket counting sort -> CSR (+ norm_in), src norms
    bucket_sort<<<NBUCK, 256, 0, stream>>>(pairD, startD, col, row_ptr, deg_arr, norm_in, n);
    bucket_norms_src<<<NBUCK, 256, 0, stream>>>(valS, startS, norm_out, n);

    // layer 1 projection (+ norm_out prescale), 4-node register blocking
    gemm1_kernel<<<(n + G1_NODES - 1) / G1_NODES, G1_BLOCK, 0, stream>>>(features, W1, norm_out,
                                                                         h1s, n);

    // gather aggregation (8 lanes/node, float4), fused epilogues
    agg1_kernel<<<(n + 31) / 32, 256, 0, stream>>>(h1s, row_ptr, deg_arr, col, norm_in,
                                                   norm_out, b1, W2, h2s, n);
    agg2_kernel<<<(n + 31) / 32, 256, 0, stream>>>(h2s, row_ptr, deg_arr, col, norm_in, b2, out, n);
}

// Round 10
// 199.125 us; speedup vs baseline: 1.0187x; 1.0187x over previous
//
#include <hip/hip_runtime.h>

#define N_NODES 100000
#define F_IN 128
#define F_HID 32
#define BN 128                  // nodes per bucket (pow2)
#define NBUCK 782               // ceil(100000/128)
#define NBLK 128                // edge partition chunks (16 entries/bucket avg -> 64B runs)
#define G1_BLOCK 128
#define G1_NODES 64             // nodes per gemm1 block

// ---------------- phase A: bucket partition of edges (no global atomics) ----------------

__global__ __launch_bounds__(256) void part_count(const int* __restrict__ src,
                                                  const int* __restrict__ dst, int E,
                                                  unsigned* __restrict__ cntD,
                                                  unsigned* __restrict__ cntS) {
    __shared__ unsigned cd[NBUCK], cs[NBUCK];
    for (int i = threadIdx.x; i < NBUCK; i += 256) { cd[i] = 0; cs[i] = 0; }
    __syncthreads();
    int chunk = (E + NBLK - 1) / NBLK;
    int e0 = blockIdx.x * chunk, e1 = min(E, e0 + chunk);
    for (int e = e0 + threadIdx.x; e < e1; e += 256) {
        atomicAdd(&cd[((unsigned)dst[e]) >> 7], 1u);   // LDS atomic
        atomicAdd(&cs[((unsigned)src[e]) >> 7], 1u);
    }
    __syncthreads();
    unsigned* od = cntD + (size_t)blockIdx.x * NBUCK;
    unsigned* os = cntS + (size_t)blockIdx.x * NBUCK;
    for (int i = threadIdx.x; i < NBUCK; i += 256) { od[i] = cd[i]; os[i] = cs[i]; }
}

// per-bucket exclusive scan over blocks (in place); totals[k] = bucket size
__global__ __launch_bounds__(NBLK) void col_scan(unsigned* __restrict__ cnt,
                                                 unsigned* __restrict__ totals) {
    __shared__ unsigned buf[2][NBLK];
    int k = blockIdx.x, t = threadIdx.x;
    unsigned v = cnt[(size_t)t * NBUCK + k];
    buf[0][t] = v;
    __syncthreads();
    int cur = 0;
    for (int off = 1; off < NBLK; off <<= 1) {
        unsigned x = buf[cur][t];
        if (t >= off) x += buf[cur][t - off];
        buf[cur ^ 1][t] = x;
        cur ^= 1;
        __syncthreads();
    }
    cnt[(size_t)t * NBUCK + k] = buf[cur][t] - v;  // exclusive over blocks
    if (t == NBLK - 1) totals[k] = buf[cur][NBLK - 1];
}

// exclusive scan of bucket totals -> start[0..NBUCK] (start[NBUCK] = E)
__global__ __launch_bounds__(1024) void total_scan(const unsigned* __restrict__ totals,
                                                   unsigned* __restrict__ start) {
    __shared__ unsigned buf[2][1024];
    int t = threadIdx.x;
    buf[0][t] = (t < NBUCK) ? totals[t] : 0;
    __syncthreads();
    int cur = 0;
    for (int off = 1; off < 1024; off <<= 1) {
        unsigned x = buf[cur][t];
        if (t >= off) x += buf[cur][t - off];
        buf[cur ^ 1][t] = x;
        cur ^= 1;
        __syncthreads();
    }
    if (t < NBUCK) start[t + 1] = buf[cur][t];
    if (t == 0) start[0] = 0;
}

// scatter edges into bucket-partitioned layout; slots disjoint by construction
__global__ __launch_bounds__(256) void part_scatter(const int* __restrict__ src,
                                                    const int* __restrict__ dst, int E,
                                                    const unsigned* __restrict__ cntD,
                                                    const unsigned* __restrict__ cntS,
                                                    const unsigned* __restrict__ startD,
                                                    const unsigned* __restrict__ startS,
                                                    unsigned* __restrict__ pairD,
                                                    unsigned* __restrict__ valS) {
    __shared__ unsigned curD[NBUCK], curS[NBUCK];
    for (int i = threadIdx.x; i < NBUCK; i += 256) { curD[i] = 0; curS[i] = 0; }
    __syncthreads();
    int chunk = (E + NBLK - 1) / NBLK;
    int e0 = blockIdx.x * chunk, e1 = min(E, e0 + chunk);
    const unsigned* bd = cntD + (size_t)blockIdx.x * NBUCK;
    const unsigned* bs = cntS + (size_t)blockIdx.x * NBUCK;
    for (int e = e0 + threadIdx.x; e < e1; e += 256) {
        unsigned s = (unsigned)src[e], d = (unsigned)dst[e];
        unsigned kd = d >> 7, ks = s >> 7;
        unsigned rd = atomicAdd(&curD[kd], 1u);                 // LDS rank
        pairD[startD[kd] + bd[kd] + rd] = s | ((d & 127u) << 17);
        unsigned rs = atomicAdd(&curS[ks], 1u);
        valS[startS[ks] + bs[ks] + rs] = s & 127u;
    }
}

// ---------------- phase B: per-bucket counting sort -> full CSR (no global atomics) ----------

__global__ __launch_bounds__(256) void bucket_sort(const unsigned* __restrict__ pairD,
                                                   const unsigned* __restrict__ startD,
                                                   int* __restrict__ col, int* __restrict__ row_ptr,
                                                   int* __restrict__ deg_arr,
                                                   float* __restrict__ norm_in, int n) {
    __shared__ unsigned cnt[BN];
    __shared__ unsigned base[BN];
    __shared__ unsigned sbuf[2][BN];
    int t = threadIdx.x;
    if (t < BN) cnt[t] = 0;
    __syncthreads();
    int k = blockIdx.x;
    unsigned a0 = startD[k], a1 = startD[k + 1];
    for (unsigned i = a0 + t; i < a1; i += 256)
        atomicAdd(&cnt[(pairD[i] >> 17) & 127u], 1u);
    __syncthreads();
    unsigned v = (t < BN) ? cnt[t] : 0;
    if (t < BN) sbuf[0][t] = v;
    __syncthreads();
    int cur = 0;
    for (int off = 1; off < BN; off <<= 1) {
        if (t < BN) {
            unsigned x = sbuf[cur][t];
            if (t >= off) x += sbuf[cur][t - off];
            sbuf[cur ^ 1][t] = x;
        }
        cur ^= 1;
        __syncthreads();
    }
    if (t < BN) {
        base[t] = a0 + sbuf[cur][t] - v;  // exclusive within bucket
        int node = k * BN + t;
        if (node < n) {
            row_ptr[node] = (int)base[t];
            deg_arr[node] = (int)v;
            norm_in[node] = rsqrtf((float)(v > 1u ? v : 1u));
        }
        cnt[t] = 0;  // reuse as cursor
    }
    __syncthreads();
    for (unsigned i = a0 + t; i < a1; i += 256) {
        unsigned pv = pairD[i];
        unsigned l = (pv >> 17) & 127u;
        unsigned r = atomicAdd(&cnt[l], 1u);   // LDS rank
        col[base[l] + r] = (int)(pv & 0x1FFFFu);
    }
}

// src-side degree -> norm_out
__global__ __launch_bounds__(256) void bucket_norms_src(const unsigned* __restrict__ valS,
                                                        const unsigned* __restrict__ startS,
                                                        float* __restrict__ norm_out, int n) {
    __shared__ unsigned cnt[BN];
    if (threadIdx.x < BN) cnt[threadIdx.x] = 0;
    __syncthreads();
    int k = blockIdx.x;
    unsigned a0 = startS[k], a1 = startS[k + 1];
    for (unsigned i = a0 + threadIdx.x; i < a1; i += 256)
        atomicAdd(&cnt[valS[i]], 1u);
    __syncthreads();
    if (threadIdx.x < BN) {
        int node = k * BN + threadIdx.x;
        if (node < n) {
            unsigned c = cnt[threadIdx.x];
            norm_out[node] = rsqrtf((float)(c > 1u ? c : 1u));
        }
    }
}

// ---------------- layer-1 projection: 4-node register blocking, x+W in LDS ----------------
// Bank-conflict-free: X rows padded to 33 float4 (bank shift 4/row); group g owns rows
// g, g+16, g+32, g+48 so the 8 groups of a wave read banks 4g..4g+3 (full 32-bank tile).

__device__ __forceinline__ void fma4(float4& a, float s, float4 w) {
    a.x += s * w.x; a.y += s * w.y; a.z += s * w.z; a.w += s * w.w;
}

__global__ __launch_bounds__(G1_BLOCK) void gemm1_kernel(const float* __restrict__ x,
                                                         const float* __restrict__ W,
                                                         const float* __restrict__ norm_out,
                                                         float* __restrict__ h, int n) {
    __shared__ float4 Xs[G1_NODES * 33];  // 33.8 KB, padded rows
    __shared__ float4 Ws[F_IN * 8];       // 16 KB
    const float4* W4 = reinterpret_cast<const float4*>(W);
    for (int i = threadIdx.x; i < F_IN * 8; i += G1_BLOCK) Ws[i] = W4[i];
    int nb = blockIdx.x * G1_NODES;
    int nrows = n - nb; if (nrows > G1_NODES) nrows = G1_NODES;
    const float4* x4 = reinterpret_cast<const float4*>(x + (size_t)nb * F_IN);
    for (int i = threadIdx.x; i < nrows * 32; i += G1_BLOCK)
        Xs[(i >> 5) * 33 + (i & 31)] = x4[i];
    __syncthreads();
    int q = threadIdx.x & 7;      // output quad: j = 4q..4q+3
    int g = threadIdx.x >> 3;     // group 0..15; nodes g+16i
    float4 acc0 = make_float4(0.f, 0.f, 0.f, 0.f);
    float4 acc1 = acc0, acc2 = acc0, acc3 = acc0;
#pragma unroll 2
    for (int k4 = 0; k4 < 32; ++k4) {
        float4 xv0 = Xs[(g + 0) * 33 + k4];
        float4 xv1 = Xs[(g + 16) * 33 + k4];
        float4 xv2 = Xs[(g + 32) * 33 + k4];
        float4 xv3 = Xs[(g + 48) * 33 + k4];
        float4 w0 = Ws[(k4 * 4 + 0) * 8 + q];
        float4 w1 = Ws[(k4 * 4 + 1) * 8 + q];
        float4 w2 = Ws[(k4 * 4 + 2) * 8 + q];
        float4 w3 = Ws[(k4 * 4 + 3) * 8 + q];
        fma4(acc0, xv0.x, w0); fma4(acc0, xv0.y, w1); fma4(acc0, xv0.z, w2); fma4(acc0, xv0.w, w3);
        fma4(acc1, xv1.x, w0); fma4(acc1, xv1.y, w1); fma4(acc1, xv1.z, w2); fma4(acc1, xv1.w, w3);
        fma4(acc2, xv2.x, w0); fma4(acc2, xv2.y, w1); fma4(acc2, xv2.z, w2); fma4(acc2, xv2.w, w3);
        fma4(acc3, xv3.x, w0); fma4(acc3, xv3.y, w1); fma4(acc3, xv3.z, w2); fma4(acc3, xv3.w, w3);
    }
    float4* h4 = reinterpret_cast<float4*>(h);
    float4 accs[4] = {acc0, acc1, acc2, acc3};
#pragma unroll
    for (int i = 0; i < 4; ++i) {
        int node = nb + g + 16 * i;
        if (node < n) {
            float no = norm_out[node];
            float4 o = accs[i];
            o.x *= no; o.y *= no; o.z *= no; o.w *= no;
            h4[(size_t)node * 8 + q] = o;
        }
    }
}

// ---------------- gather aggregation: 8 lanes/node, float4/lane, 8-edge unroll --------------

__device__ __forceinline__ float4 shfl4_8(float4 v, int sl) {
    float4 r;
    r.x = __shfl(v.x, sl, 8);
    r.y = __shfl(v.y, sl, 8);
    r.z = __shfl(v.z, sl, 8);
    r.w = __shfl(v.w, sl, 8);
    return r;
}

// layer 1: agg + norm_in + b1 + relu, GEMM2 (8-lane shfl), prescale norm_out -> h2s
__global__ __launch_bounds__(256) void agg1_kernel(const float* __restrict__ h1s,
                                                   const int* __restrict__ row_ptr,
                                                   const int* __restrict__ deg_arr,
                                                   const int* __restrict__ col,
                                                   const float* __restrict__ norm_in,
                                                   const float* __restrict__ norm_out,
                                                   const float* __restrict__ b1,
                                                   const float* __restrict__ W2,
                                                   float* __restrict__ h2s, int n) {
    __shared__ float W2l[F_HID * F_HID];  // row k holds W2[k][0..31]
    for (int i = threadIdx.x; i < F_HID * F_HID; i += 256) W2l[i] = W2[i];
    __syncthreads();
    const float4* h4 = reinterpret_cast<const float4*>(h1s);
    const float4* W24 = reinterpret_cast<const float4*>(W2l);
    int q = threadIdx.x & 7;                 // lane in 8-lane group
    int node = blockIdx.x * 32 + (threadIdx.x >> 3);
    if (node >= n) return;
    int start = row_ptr[node];
    int deg = deg_arr[node];
    float4 acc = make_float4(0.f, 0.f, 0.f, 0.f);
    int jj = 0;
    for (; jj + 8 <= deg; jj += 8) {
        int c = col[start + jj + q];         // 8 lanes: one coalesced 32B load
#pragma unroll
        for (int m = 0; m < 8; ++m) {
            int s = __shfl(c, m, 8);
            float4 v = h4[(size_t)s * 8 + q];
            acc.x += v.x; acc.y += v.y; acc.z += v.z; acc.w += v.w;
        }
    }
    int rem = deg - jj;
    if (rem > 0) {
        int c = col[start + jj + (q < rem ? q : 0)];
        for (int m = 0; m < rem; ++m) {
            int s = __shfl(c, m, 8);
            float4 v = h4[(size_t)s * 8 + q];
            acc.x += v.x; acc.y += v.y; acc.z += v.z; acc.w += v.w;
        }
    }
    float ni = norm_in[node];
    const float4 b14 = reinterpret_cast<const float4*>(b1)[q];
    float4 t;
    t.x = fmaxf(acc.x * ni + b14.x, 0.f);
    t.y = fmaxf(acc.y * ni + b14.y, 0.f);
    t.z = fmaxf(acc.z * ni + b14.z, 0.f);
    t.w = fmaxf(acc.w * ni + b14.w, 0.f);
    // GEMM2: o[f] = sum_k t[k] * W2[k][f]; t distributed 4-per-lane over 8 lanes
    float4 o = make_float4(0.f, 0.f, 0.f, 0.f);
#pragma unroll
    for (int sl = 0; sl < 8; ++sl) {
        float4 tt = shfl4_8(t, sl);
        int kb = sl * 4;
        float4 w0 = W24[(kb + 0) * 8 + q];
        float4 w1 = W24[(kb + 1) * 8 + q];
        float4 w2 = W24[(kb + 2) * 8 + q];
        float4 w3 = W24[(kb + 3) * 8 + q];
        o.x += tt.x * w0.x + tt.y * w1.x + tt.z * w2.x + tt.w * w3.x;
        o.y += tt.x * w0.y + tt.y * w1.y + tt.z * w2.y + tt.w * w3.y;
        o.z += tt.x * w0.z + tt.y * w1.z + tt.z * w2.z + tt.w * w3.z;
        o.w += tt.x * w0.w + tt.y * w1.w + tt.z * w2.w + tt.w * w3.w;
    }
    float no = norm_out[node];
    o.x *= no; o.y *= no; o.z *= no; o.w *= no;
    reinterpret_cast<float4*>(h2s)[(size_t)node * 8 + q] = o;
}

// layer 2: agg + norm_in + b2 -> out
__global__ __launch_bounds__(256) void agg2_kernel(const float* __restrict__ h2s,
                                                   const int* __restrict__ row_ptr,
                                                   const int* __restrict__ deg_arr,
                                                   const int* __restrict__ col,
                                                   const float* __restrict__ norm_in,
                                                   const float* __restrict__ b2,
                                                   float* __restrict__ out, int n) {
    const float4* h4 = reinterpret_cast<const float4*>(h2s);
    int q = threadIdx.x & 7;
    int node = blockIdx.x * 32 + (threadIdx.x >> 3);
    if (node >= n) return;
    int start = row_ptr[node];
    int deg = deg_arr[node];
    float4 acc = make_float4(0.f, 0.f, 0.f, 0.f);
    int jj = 0;
    for (; jj + 8 <= deg; jj += 8) {
        int c = col[start + jj + q];
#pragma unroll
        for (int m = 0; m < 8; ++m) {
            int s = __shfl(c, m, 8);
            float4 v = h4[(size_t)s * 8 + q];
            acc.x += v.x; acc.y += v.y; acc.z += v.z; acc.w += v.w;
        }
    }
    int rem = deg - jj;
    if (rem > 0) {
        int c = col[start + jj + (q < rem ? q : 0)];
        for (int m = 0; m < rem; ++m) {
            int s = __shfl(c, m, 8);
            float4 v = h4[(size_t)s * 8 + q];
            acc.x += v.x; acc.y += v.y; acc.z += v.z; acc.w += v.w;
        }
    }
    float ni = norm_in[node];
    const float4 b24 = reinterpret_cast<const float4*>(b2)[q];
    float4 o;
    o.x = acc.x * ni + b24.x;
    o.y = acc.y * ni + b24.y;
    o.z = acc.z * ni + b24.z;
    o.w = acc.w * ni + b24.w;
    reinterpret_cast<float4*>(out)[(size_t)node * 8 + q] = o;
}

// ---------------- launch ----------------

static inline size_t align256(size_t x) { return (x + 255) & ~(size_t)255; }

extern "C" void kernel_launch(void* const* d_in, const int* in_sizes, int n_in,
                              void* d_out, int out_size, void* d_ws, size_t ws_size,
                              hipStream_t stream) {
    const float* features = (const float*)d_in[0];
    const float* W1 = (const float*)d_in[1];
    const float* b1 = (const float*)d_in[2];
    const float* W2 = (const float*)d_in[3];
    const float* b2 = (const float*)d_in[4];
    const int* src = (const int*)d_in[5];
    const int* dst = (const int*)d_in[6];
    const int E = in_sizes[5];
    const int n = N_NODES;
    float* out = (float*)d_out;

    char* ws = (char*)d_ws;
    size_t off = 0;
    float* norm_out = (float*)(ws + off); off += align256((size_t)n * 4);
    float* norm_in = (float*)(ws + off);  off += align256((size_t)n * 4);
    int* row_ptr = (int*)(ws + off);      off += align256((size_t)n * 4);
    int* deg_arr = (int*)(ws + off);      off += align256((size_t)n * 4);
    unsigned* startD = (unsigned*)(ws + off); off += align256((NBUCK + 1) * 4);
    unsigned* startS = (unsigned*)(ws + off); off += align256((NBUCK + 1) * 4);
    unsigned* totD = (unsigned*)(ws + off);   off += align256(NBUCK * 4);
    unsigned* totS = (unsigned*)(ws + off);   off += align256(NBUCK * 4);
    int* col = (int*)(ws + off);              off += align256((size_t)E * 4);  // 6.4 MB

    // region X: pairD+valS (live: part_scatter -> bucket kernels) then h2s (live: agg1 -> agg2)
    size_t regX = off;
    unsigned* pairD = (unsigned*)(ws + regX);                        // 6.4 MB
    unsigned* valS = (unsigned*)(ws + regX + (size_t)E * 4);         // 6.4 MB
    float* h2s = (float*)(ws + regX);                                // 12.8 MB
    off += align256((size_t)2 * E * 4);
    // region Y: cntD+cntS (live: part_count -> part_scatter) then h1s (live: gemm1 -> agg1)
    size_t regY = off;
    unsigned* cntD = (unsigned*)(ws + regY);                         // 0.4 MB
    unsigned* cntS = (unsigned*)(ws + regY + (size_t)NBLK * NBUCK * 4);
    float* h1s = (float*)(ws + regY);                                // 12.8 MB

    // phase A: partition edges by dst-bucket (pairs) and src-bucket (locals)
    part_count<<<NBLK, 256, 0, stream>>>(src, dst, E, cntD, cntS);
    col_scan<<<NBUCK, NBLK, 0, stream>>>(cntD, totD);
    col_scan<<<NBUCK, NBLK, 0, stream>>>(cntS, totS);
    total_scan<<<1, 1024, 0, stream>>>(totD, startD);
    total_scan<<<1, 1024, 0, stream>>>(totS, startS);
    part_scatter<<<NBLK, 256, 0, stream>>>(src, dst, E, cntD, cntS, startD, startS, pairD, valS);

    // phase B: per-bucket counting sort -> CSR (+ norm_in), src norms
    bucket_sort<<<NBUCK, 256, 0, stream>>>(pairD, startD, col, row_ptr, deg_arr, norm_in, n);
    bucket_norms_src<<<NBUCK, 256, 0, stream>>>(valS, startS, norm_out, n);

    // layer 1 projection (+ norm_out prescale), 4-node register blocking, conflict-free LDS
    gemm1_kernel<<<(n + G1_NODES - 1) / G1_NODES, G1_BLOCK, 0, stream>>>(features, W1, norm_out,
                                                                         h1s, n);

    // gather aggregation (8 lanes/node, float4), fused epilogues
    agg1_kernel<<<(n + 31) / 32, 256, 0, stream>>>(h1s, row_ptr, deg_arr, col, norm_in,
                                                   norm_out, b1, W2, h2s, n);
    agg2_kernel<<<(n + 31) / 32, 256, 0, stream>>>(h2s, row_ptr, deg_arr, col, norm_in, b2, out, n);
}